// Round 15
// baseline (123.190 us; speedup 1.0000x reference)
//
#include <hip/hip_runtime.h>
#include <hip/hip_bf16.h>
#include <stdint.h>

typedef int i32x4 __attribute__((ext_vector_type(4)));
typedef int i32x8 __attribute__((ext_vector_type(8)));
typedef float f32x4 __attribute__((ext_vector_type(4)));

// ---------------------------------------------------------------------------
// Pass 1: binarize f32 -> fp4 e2m1 sign nibble (+1=0x2, -1=0xA, 0=0x0),
// packed 2 elems/byte, low nibble = lower k index.
// Round 15: restore the R6-PROVEN shape -- the only binarize configuration
// measured at HBM-class rate (~40 us pair for 251 MB in round 6): TWO
// separate grid-stride dispatches (2048 blocks x 256), per iter each thread
// loads 4 independent float4 (64 B) and stores ONE uint2 (8 B/lane = 512
// B/wave-store). The fused fp4 variants (R12-R14, 4B/2B lane-stores) all
// sat at ~3 TB/s; read-pattern and MLP changes were measured ~null, so the
// remaining variables are store width + dispatch shape -- this restores both.
// ---------------------------------------------------------------------------
__device__ __forceinline__ unsigned int sign_nib(float x) {
  return x > 0.0f ? 0x2u : (x < 0.0f ? 0xAu : 0x0u);
}

__device__ __forceinline__ unsigned int pack8(const float4& a, const float4& b) {
  return sign_nib(a.x)
       | (sign_nib(a.y) << 4)
       | (sign_nib(a.z) << 8)
       | (sign_nib(a.w) << 12)
       | (sign_nib(b.x) << 16)
       | (sign_nib(b.y) << 20)
       | (sign_nib(b.z) << 24)
       | (sign_nib(b.w) << 28);
}

__global__ __launch_bounds__(256)
void binarize_fp4(const float* __restrict__ in,
                  uint2* __restrict__ out,
                  int ngroups) {   // ngroups = count of 16-float groups
  int idx = blockIdx.x * blockDim.x + threadIdx.x;
  int stride = gridDim.x * blockDim.x;
  const float4* in4 = (const float4*)in;
  for (int g = idx; g < ngroups; g += stride) {
    float4 v0 = in4[4 * g];
    float4 v1 = in4[4 * g + 1];
    float4 v2 = in4[4 * g + 2];
    float4 v3 = in4[4 * g + 3];
    uint2 o;
    o.x = pack8(v0, v1);   // elems 0..7  (bytes 0-3, low nibble = lower k)
    o.y = pack8(v2, v3);   // elems 8..15 (bytes 4-7)
    out[g] = o;
  }
}

// ---------------------------------------------------------------------------
// Pass 2: C = A * B^T, fp4 +-1/0 inputs, MX-scaled MFMA (scale=1.0), f32 out.
// EXACT: products are +-1/0, f32 accumulation of <=4096 integers is exact.
// UNCHANGED since round 12 (steady-state ~43 us ~= 93% of the fp4 16x16
// MFMA ubench ceiling 7228 TF; conflicts 0 -- at its structural roofline).
// 256x256 tile, BK=128 fp4 (64 B/row), 8 waves (2Mx4N), 4-buffer LDS
// rotation, counted vmcnt, ONE asm barrier per tile, stage(tt+2) after
// the barrier. nt = 32.
// ---------------------------------------------------------------------------
__device__ __forceinline__ void load_lds16(const void* g, void* l) {
  __builtin_amdgcn_global_load_lds(
      (const __attribute__((address_space(1))) void*)g,
      (__attribute__((address_space(3))) void*)l,
      16, 0, 0);
}

__device__ __forceinline__ void bar() {
  asm volatile("s_barrier" ::: "memory");
}
template <int N>
__device__ __forceinline__ void waitvm() {
  asm volatile("s_waitcnt vmcnt(%0)" ::"i"(N) : "memory");
}

__device__ __forceinline__ i32x8 rd8(const char* p) {
  i32x4 q = *(const i32x4*)p;
  return __builtin_shufflevector(q, q, 0, 1, 2, 3, -1, -1, -1, -1);
}

__global__ __launch_bounds__(512, 2)
void gemm_bt_fp4(const unsigned char* __restrict__ A,
                 const unsigned char* __restrict__ B,
                 float* __restrict__ C,
                 int M, int N, int K, int nbn) {
  constexpr int BM = 256, BN = 256;
  __shared__ __attribute__((aligned(16))) char lds[4 * 32768];

  // XCD-aware bijective swizzle (grid = 32*16 = 512, multiple of 8)
  int nwg = gridDim.x;
  int bid = blockIdx.x;
  int cpx = nwg >> 3;
  int swz = (bid & 7) * cpx + (bid >> 3);
  int tm = swz / nbn;
  int tn = swz % nbn;

  const int t = threadIdx.x;
  const int lane = t & 63;
  const int wid = t >> 6;       // 0..7
  const int wm = wid >> 2;      // 0..1  (wave row: 128 rows)
  const int wn = wid & 3;       // 0..3  (wave col: 64 cols)
  const int lrow = lane & 15;
  const int kg = lane >> 4;     // 0..3 (32 contiguous fp4 k-elems = 16 B)

  const int Kb = K >> 1;        // row stride in bytes (fp4 packed)
  const size_t rowA0 = (size_t)tm * BM;
  const size_t rowB0 = (size_t)tn * BN;

  f32x4 acc[8][4] = {};

  const int nt = K / 128;  // 32

  // --- staging lane constants (inverse-swizzled global source) ---
  const int soff0 = wid * 1024 + lane * 16;
  const int srow0 = soff0 >> 6;
  const int scb0 = ((soff0 >> 4) & 3) ^ ((srow0 >> 1) & 3);
  const int soff1 = 8192 + wid * 1024 + lane * 16;
  const int srow1 = soff1 >> 6;
  const int scb1 = ((soff1 >> 4) & 3) ^ ((srow1 >> 1) & 3);

  auto stage = [&](int tt) {
    const int b = tt & 3;
    const int k0b = tt * 64;    // tile K-offset in BYTES (128 fp4 = 64 B)
    load_lds16(A + (rowA0 + srow0) * Kb + k0b + scb0 * 16,
               lds + b * 32768 + wid * 1024);
    load_lds16(A + (rowA0 + srow1) * Kb + k0b + scb1 * 16,
               lds + b * 32768 + 8192 + wid * 1024);
    load_lds16(B + (rowB0 + srow0) * Kb + k0b + scb0 * 16,
               lds + b * 32768 + 16384 + wid * 1024);
    load_lds16(B + (rowB0 + srow1) * Kb + k0b + scb1 * 16,
               lds + b * 32768 + 16384 + 8192 + wid * 1024);
  };

  // --- swizzled read column (byte) within a 64B LDS row (proven 0-conflict)
  const int rcol = ((kg ^ ((lrow >> 1) & 3)) << 4);
  const int aoff = (wm * 128 + lrow) * 64 + rcol;
  const int boff = 16384 + (wn * 64 + lrow) * 64 + rcol;

  const int SC = 0x7F7F7F7F;  // E8M0 scale bytes: 127 -> 2^0

  // prologue: stage tiles 0 and 1 (8 loads outstanding per thread)
  stage(0); stage(1);

  for (int tt = 0; tt < nt; ++tt) {
    const int b = tt & 3;
    if (tt + 1 < nt) waitvm<4>(); else waitvm<0>();
    bar();  // the only barrier per tile

    const char* Ab = lds + b * 32768 + aoff;
    const char* Bb = lds + b * 32768 + boff;

    // half-phase 1: B frags + A frags 0..3, restage, 16 MFMAs
    i32x8 bf[4], af[4];
    #pragma unroll
    for (int n = 0; n < 4; ++n)
      bf[n] = rd8(Bb + n * 1024);
    #pragma unroll
    for (int m = 0; m < 4; ++m)
      af[m] = rd8(Ab + m * 1024);

    if (tt + 2 < nt) stage(tt + 2);

    #pragma unroll
    for (int m = 0; m < 4; ++m)
      #pragma unroll
      for (int n = 0; n < 4; ++n)
        acc[m][n] = __builtin_amdgcn_mfma_scale_f32_16x16x128_f8f6f4(
            af[m], bf[n], acc[m][n], 4, 4, 0, SC, 0, SC);

    // half-phase 2: A frags 4..7, 16 MFMAs
    i32x8 ag[4];
    #pragma unroll
    for (int m = 0; m < 4; ++m)
      ag[m] = rd8(Ab + (m + 4) * 1024);

    #pragma unroll
    for (int m = 0; m < 4; ++m)
      #pragma unroll
      for (int n = 0; n < 4; ++n)
        acc[m + 4][n] = __builtin_amdgcn_mfma_scale_f32_16x16x128_f8f6f4(
            ag[m], bf[n], acc[m + 4][n], 4, 4, 0, SC, 0, SC);
  }

  // --- epilogue: 16x16 C/D layout col = lane&15, row = (lane>>4)*4 + r ---
  const size_t cRow0 = rowA0 + (size_t)wm * 128;
  const size_t cCol0 = rowB0 + (size_t)wn * 64;
  const int orow = kg * 4;
  #pragma unroll
  for (int m = 0; m < 8; ++m)
    #pragma unroll
    for (int n = 0; n < 4; ++n)
      #pragma unroll
      for (int r = 0; r < 4; ++r)
        C[(cRow0 + m * 16 + orow + r) * N + cCol0 + n * 16 + lrow] =
            acc[m][n][r];
}

// ---------------------------------------------------------------------------
extern "C" void kernel_launch(void* const* d_in, const int* in_sizes, int n_in,
                              void* d_out, int out_size, void* d_ws, size_t ws_size,
                              hipStream_t stream) {
  const float* x = (const float*)d_in[0];
  const float* w = (const float*)d_in[1];
  float* out = (float*)d_out;

  const int K = 4096;
  const int M = in_sizes[0] / K;   // 8192
  const int N = in_sizes[1] / K;   // 4096

  unsigned char* xb = (unsigned char*)d_ws;
  unsigned char* wb = xb + (size_t)M * (K / 2);

  // two dispatches, R6-proven shape: 2048 blocks x 256, grid-stride,
  // 16 floats -> uint2 per iter (x: 4 iters, w: 2 iters, no remainder)
  int gx = (M * K) / 16;           // 2097152
  int gw = (N * K) / 16;           // 1048576
  binarize_fp4<<<dim3(2048), dim3(256), 0, stream>>>(x, (uint2*)xb, gx);
  binarize_fp4<<<dim3(2048), dim3(256), 0, stream>>>(w, (uint2*)wb, gw);

  int nbm = M / 256;  // 32
  int nbn = N / 256;  // 16
  gemm_bt_fp4<<<dim3(nbm * nbn), dim3(512), 0, stream>>>(
      xb, wb, out, M, N, K, nbn);
}

// Round 16
// 122.592 us; speedup vs baseline: 1.0049x; 1.0049x over previous
//
#include <hip/hip_runtime.h>
#include <hip/hip_bf16.h>
#include <stdint.h>

typedef int i32x4 __attribute__((ext_vector_type(4)));
typedef int i32x8 __attribute__((ext_vector_type(8)));
typedef float f32x4 __attribute__((ext_vector_type(4)));

// ---------------------------------------------------------------------------
// Pass 1: binarize f32 -> fp4 e2m1 sign nibble (+1=0x2, -1=0xA, 0=0x0),
// packed 2 elems/byte, low nibble = lower k index.
// Round 16: DETERMINISTIC software pipeline. All fp4 variants (R12-R15) sat
// at ~2.6-3 TB/s regardless of access shape; the shared skeleton was a
// runtime-trip-count grid-stride loop whose body serializes
// {loads -> vmcnt(0) -> pack -> store} unless the compiler happens to
// pipeline it (R6's i8 build did -> 7 TB/s; these builds didn't).
// Now: compile-time ITERS, fully unrolled, ALL loads (16 for x, 8 for w)
// issued in one burst before any pack -- 256 B/lane in flight, static
// register indices. Lane-contiguous 1 KB wave-spans per load instruction,
// uint2 stores (proven-correct byte/nibble order, unchanged).
// ---------------------------------------------------------------------------
__device__ __forceinline__ unsigned int sign_nib(float x) {
  return x > 0.0f ? 0x2u : (x < 0.0f ? 0xAu : 0x0u);
}

__device__ __forceinline__ unsigned int pack8(const float4& a, const float4& b) {
  return sign_nib(a.x)
       | (sign_nib(a.y) << 4)
       | (sign_nib(a.z) << 8)
       | (sign_nib(a.w) << 12)
       | (sign_nib(b.x) << 16)
       | (sign_nib(b.y) << 20)
       | (sign_nib(b.z) << 24)
       | (sign_nib(b.w) << 28);
}

template <int ITERS>
__global__ __launch_bounds__(256)
void binarize_fp4_pipe(const float* __restrict__ in,
                       uint2* __restrict__ out) {
  const int S = gridDim.x * blockDim.x;          // thread count = groups/ITERS
  const int g0 = blockIdx.x * blockDim.x + threadIdx.x;
  const float4* in4 = (const float4*)in;

  float4 v[ITERS][4];
  // burst-issue every load before any consume (16 or 8 independent dwordx4)
  #pragma unroll
  for (int k = 0; k < ITERS; ++k) {
    const size_t gk = (size_t)g0 + (size_t)k * S;
    #pragma unroll
    for (int j = 0; j < 4; ++j)
      v[k][j] = in4[4 * gk + j];
  }
  #pragma unroll
  for (int k = 0; k < ITERS; ++k) {
    const size_t gk = (size_t)g0 + (size_t)k * S;
    uint2 o;
    o.x = pack8(v[k][0], v[k][1]);   // elems 0..7  (low nibble = lower k)
    o.y = pack8(v[k][2], v[k][3]);   // elems 8..15
    out[gk] = o;
  }
}

// ---------------------------------------------------------------------------
// Pass 2: C = A * B^T, fp4 +-1/0 inputs, MX-scaled MFMA (scale=1.0), f32 out.
// EXACT: products are +-1/0, f32 accumulation of <=4096 integers is exact.
// UNCHANGED since round 12 (steady-state ~43 us ~= 93% of the fp4 16x16
// MFMA ubench ceiling 7228 TF; conflicts 0 -- at its structural roofline).
// 256x256 tile, BK=128 fp4 (64 B/row), 8 waves (2Mx4N), 4-buffer LDS
// rotation, counted vmcnt, ONE asm barrier per tile, stage(tt+2) after
// the barrier. nt = 32.
// ---------------------------------------------------------------------------
__device__ __forceinline__ void load_lds16(const void* g, void* l) {
  __builtin_amdgcn_global_load_lds(
      (const __attribute__((address_space(1))) void*)g,
      (__attribute__((address_space(3))) void*)l,
      16, 0, 0);
}

__device__ __forceinline__ void bar() {
  asm volatile("s_barrier" ::: "memory");
}
template <int N>
__device__ __forceinline__ void waitvm() {
  asm volatile("s_waitcnt vmcnt(%0)" ::"i"(N) : "memory");
}

__device__ __forceinline__ i32x8 rd8(const char* p) {
  i32x4 q = *(const i32x4*)p;
  return __builtin_shufflevector(q, q, 0, 1, 2, 3, -1, -1, -1, -1);
}

__global__ __launch_bounds__(512, 2)
void gemm_bt_fp4(const unsigned char* __restrict__ A,
                 const unsigned char* __restrict__ B,
                 float* __restrict__ C,
                 int M, int N, int K, int nbn) {
  constexpr int BM = 256, BN = 256;
  __shared__ __attribute__((aligned(16))) char lds[4 * 32768];

  // XCD-aware bijective swizzle (grid = 32*16 = 512, multiple of 8)
  int nwg = gridDim.x;
  int bid = blockIdx.x;
  int cpx = nwg >> 3;
  int swz = (bid & 7) * cpx + (bid >> 3);
  int tm = swz / nbn;
  int tn = swz % nbn;

  const int t = threadIdx.x;
  const int lane = t & 63;
  const int wid = t >> 6;       // 0..7
  const int wm = wid >> 2;      // 0..1  (wave row: 128 rows)
  const int wn = wid & 3;       // 0..3  (wave col: 64 cols)
  const int lrow = lane & 15;
  const int kg = lane >> 4;     // 0..3 (32 contiguous fp4 k-elems = 16 B)

  const int Kb = K >> 1;        // row stride in bytes (fp4 packed)
  const size_t rowA0 = (size_t)tm * BM;
  const size_t rowB0 = (size_t)tn * BN;

  f32x4 acc[8][4] = {};

  const int nt = K / 128;  // 32

  // --- staging lane constants (inverse-swizzled global source) ---
  const int soff0 = wid * 1024 + lane * 16;
  const int srow0 = soff0 >> 6;
  const int scb0 = ((soff0 >> 4) & 3) ^ ((srow0 >> 1) & 3);
  const int soff1 = 8192 + wid * 1024 + lane * 16;
  const int srow1 = soff1 >> 6;
  const int scb1 = ((soff1 >> 4) & 3) ^ ((srow1 >> 1) & 3);

  auto stage = [&](int tt) {
    const int b = tt & 3;
    const int k0b = tt * 64;    // tile K-offset in BYTES (128 fp4 = 64 B)
    load_lds16(A + (rowA0 + srow0) * Kb + k0b + scb0 * 16,
               lds + b * 32768 + wid * 1024);
    load_lds16(A + (rowA0 + srow1) * Kb + k0b + scb1 * 16,
               lds + b * 32768 + 8192 + wid * 1024);
    load_lds16(B + (rowB0 + srow0) * Kb + k0b + scb0 * 16,
               lds + b * 32768 + 16384 + wid * 1024);
    load_lds16(B + (rowB0 + srow1) * Kb + k0b + scb1 * 16,
               lds + b * 32768 + 16384 + 8192 + wid * 1024);
  };

  // --- swizzled read column (byte) within a 64B LDS row (proven 0-conflict)
  const int rcol = ((kg ^ ((lrow >> 1) & 3)) << 4);
  const int aoff = (wm * 128 + lrow) * 64 + rcol;
  const int boff = 16384 + (wn * 64 + lrow) * 64 + rcol;

  const int SC = 0x7F7F7F7F;  // E8M0 scale bytes: 127 -> 2^0

  // prologue: stage tiles 0 and 1 (8 loads outstanding per thread)
  stage(0); stage(1);

  for (int tt = 0; tt < nt; ++tt) {
    const int b = tt & 3;
    if (tt + 1 < nt) waitvm<4>(); else waitvm<0>();
    bar();  // the only barrier per tile

    const char* Ab = lds + b * 32768 + aoff;
    const char* Bb = lds + b * 32768 + boff;

    // half-phase 1: B frags + A frags 0..3, restage, 16 MFMAs
    i32x8 bf[4], af[4];
    #pragma unroll
    for (int n = 0; n < 4; ++n)
      bf[n] = rd8(Bb + n * 1024);
    #pragma unroll
    for (int m = 0; m < 4; ++m)
      af[m] = rd8(Ab + m * 1024);

    if (tt + 2 < nt) stage(tt + 2);

    #pragma unroll
    for (int m = 0; m < 4; ++m)
      #pragma unroll
      for (int n = 0; n < 4; ++n)
        acc[m][n] = __builtin_amdgcn_mfma_scale_f32_16x16x128_f8f6f4(
            af[m], bf[n], acc[m][n], 4, 4, 0, SC, 0, SC);

    // half-phase 2: A frags 4..7, 16 MFMAs
    i32x8 ag[4];
    #pragma unroll
    for (int m = 0; m < 4; ++m)
      ag[m] = rd8(Ab + (m + 4) * 1024);

    #pragma unroll
    for (int m = 0; m < 4; ++m)
      #pragma unroll
      for (int n = 0; n < 4; ++n)
        acc[m + 4][n] = __builtin_amdgcn_mfma_scale_f32_16x16x128_f8f6f4(
            ag[m], bf[n], acc[m + 4][n], 4, 4, 0, SC, 0, SC);
  }

  // --- epilogue: 16x16 C/D layout col = lane&15, row = (lane>>4)*4 + r ---
  const size_t cRow0 = rowA0 + (size_t)wm * 128;
  const size_t cCol0 = rowB0 + (size_t)wn * 64;
  const int orow = kg * 4;
  #pragma unroll
  for (int m = 0; m < 8; ++m)
    #pragma unroll
    for (int n = 0; n < 4; ++n)
      #pragma unroll
      for (int r = 0; r < 4; ++r)
        C[(cRow0 + m * 16 + orow + r) * N + cCol0 + n * 16 + lrow] =
            acc[m][n][r];
}

// ---------------------------------------------------------------------------
extern "C" void kernel_launch(void* const* d_in, const int* in_sizes, int n_in,
                              void* d_out, int out_size, void* d_ws, size_t ws_size,
                              hipStream_t stream) {
  const float* x = (const float*)d_in[0];
  const float* w = (const float*)d_in[1];
  float* out = (float*)d_out;

  const int K = 4096;
  const int M = in_sizes[0] / K;   // 8192
  const int N = in_sizes[1] / K;   // 4096

  unsigned char* xb = (unsigned char*)d_ws;
  unsigned char* wb = xb + (size_t)M * (K / 2);

  // x: 2,097,152 groups of 16 floats = 4 iters x 524288 threads (2048 blocks)
  // w: 1,048,576 groups               = 2 iters x 524288 threads
  binarize_fp4_pipe<4><<<dim3(2048), dim3(256), 0, stream>>>(x, (uint2*)xb);
  binarize_fp4_pipe<2><<<dim3(2048), dim3(256), 0, stream>>>(w, (uint2*)wb);

  int nbm = M / 256;  // 32
  int nbn = N / 256;  // 16
  gemm_bt_fp4<<<dim3(nbm * nbn), dim3(512), 0, stream>>>(
      xb, wb, out, M, N, K, nbn);
}